// Round 14
// baseline (346.336 us; speedup 1.0000x reference)
//
#include <hip/hip_runtime.h>

#define B_    32
#define C_    192
#define N_    784
#define NP_   1024        // padded candidate dim
#define K_    9
#define COUT_ 384
#define NPTS_ (B_ * N_)   // 25088
#define QPB_  32          // queries per knn block (2 MFMA row-groups)
#define NTILES_ 224       // 32 b * 7 ntiles

typedef __attribute__((ext_vector_type(8))) short short8;   // 8 bf16 = 4 VGPR
typedef __attribute__((ext_vector_type(4))) float f32x4;    // MFMA acc

// ordered-uint transform: monotone map float -> uint
__device__ __forceinline__ unsigned int ford(float f) {
  unsigned int u = __float_as_uint(f);
  return u ^ ((u & 0x80000000u) ? 0xFFFFFFFFu : 0x80000000u);
}
// fp32 -> bf16 (RNE) without library types
__device__ __forceinline__ unsigned short f2bf(float f) {
  unsigned int u = __float_as_uint(f);
  u += 0x7FFFu + ((u >> 16) & 1u);
  return (unsigned short)(u >> 16);
}
__device__ __forceinline__ float bf2f(unsigned short h) {
  return __uint_as_float(((unsigned int)h) << 16);
}

// ---------------------------------------------------------------------------
// K0: zero xnT pad cols, set sqp pad to +1e30 — every launch.
// ---------------------------------------------------------------------------
__global__ __launch_bounds__(256) void pad_kernel(
    float* __restrict__ xnT, float* __restrict__ sqp) {
  int i = blockIdx.x * 256 + threadIdx.x;
  const int npad = B_ * C_ * (NP_ - N_);
  if (i < npad) {
    int j  = i % (NP_ - N_);
    int cc = (i / (NP_ - N_)) % C_;
    int bb = i / ((NP_ - N_) * C_);
    xnT[((size_t)bb * C_ + cc) * NP_ + N_ + j] = 0.f;
  }
  int s = i - npad;
  if (s >= 0 && s < B_ * (NP_ - N_)) {
    int j = s % (NP_ - N_), bb = s / (NP_ - N_);
    sqp[(size_t)bb * NP_ + N_ + j] = 1e30f;
  }
}

// ---------------------------------------------------------------------------
// K1: parallel norm. Block = 64 points x 4 c-groups. Writes xnT fp32 + sqp.
// ---------------------------------------------------------------------------
__global__ __launch_bounds__(256) void norm_kernel(
    const float* __restrict__ x, float* __restrict__ xnT,
    float* __restrict__ sqp) {
  int t = threadIdx.x;
  int pl = t & 63, cg = t >> 6;
  int p = blockIdx.x * 64 + pl;
  int b = p / N_, n = p % N_;
  const float* xb = x + (size_t)b * C_ * N_ + n;

  __shared__ float red[4][64];
  __shared__ float nrmS[64];

  float part = 0.f;
  #pragma unroll 8
  for (int j = 0; j < 48; j++) {
    float v = xb[(size_t)(cg * 48 + j) * N_];
    part = __fmaf_rn(v, v, part);
  }
  red[cg][pl] = part;
  __syncthreads();
  if (t < 64) {
    float ssq = __fadd_rn(__fadd_rn(red[0][t], red[1][t]),
                          __fadd_rn(red[2][t], red[3][t]));
    nrmS[t] = fmaxf(__fsqrt_rn(ssq), 1e-12f);
  }
  __syncthreads();
  float nrm = nrmS[pl];
  float* xt = xnT + (size_t)b * C_ * NP_ + n;
  float p2 = 0.f;
  #pragma unroll 8
  for (int j = 0; j < 48; j++) {
    float a = __fdiv_rn(xb[(size_t)(cg * 48 + j) * N_], nrm);
    xt[(size_t)(cg * 48 + j) * NP_] = a;
    p2 = __fmaf_rn(a, a, p2);
  }
  red[cg][pl] = p2;
  __syncthreads();
  if (t < 64) {
    float sq = __fadd_rn(__fadd_rn(red[0][t], red[1][t]),
                         __fadd_rn(red[2][t], red[3][t]));
    int pp = blockIdx.x * 64 + t;
    sqp[(size_t)(pp / N_) * NP_ + (pp % N_)] = sq;
  }
}

// ---------------------------------------------------------------------------
// K2: pack xnT into MFMA fragment buffers, split bf16 (hi, lo).
// ---------------------------------------------------------------------------
__global__ __launch_bounds__(256) void pack_kernel(
    const float* __restrict__ xnT, short8* __restrict__ fragH,
    short8* __restrict__ fragL) {
  int mc = blockIdx.x, ks = blockIdx.y, b = blockIdx.z;
  int t = threadIdx.x;
  __shared__ float T[32][133];

  const float* src = xnT + (size_t)b * C_ * NP_ + (size_t)(ks * 32) * NP_
                     + mc * 128;
  for (int i = t; i < 32 * 128; i += 256)
    T[i >> 7][i & 127] = src[(size_t)(i >> 7) * NP_ + (i & 127)];
  __syncthreads();

  for (int e = t; e < 512; e += 256) {
    int g = e >> 6, l = e & 63;
    int colL = l & 15, kq = l >> 4;
    union { short8 v; unsigned short u[8]; } ph, pl2;
    #pragma unroll
    for (int j = 0; j < 8; j++) {
      float v = T[kq * 8 + j][g * 16 + colL];
      unsigned short h = f2bf(v);
      ph.u[j]  = h;
      pl2.u[j] = f2bf(__fsub_rn(v, bf2f(h)));
    }
    size_t idx = (((size_t)b * 6 + ks) * 64 + (mc * 8 + g)) * 64 + l;
    fragH[idx] = ph.v;
    fragL[idx] = pl2.v;
  }
}

// ---------------------------------------------------------------------------
// K3: MFMA KNN, QPB=32 (2 row-groups). Block = 32 q x 1024 cand, 4 waves.
//  grp0 rows -> dkS -> select (pass 1); grp1 keys held in 64 regs (full
//  unroll -> static indexing), written + selected in pass 2 (q<784 guard).
//  Distances bit-identical to R13 (same MFMA chains, same extraction).
// ---------------------------------------------------------------------------
__global__ __launch_bounds__(256) void knn_kernel(
    const short8* __restrict__ fragH, const short8* __restrict__ fragL,
    const float* __restrict__ sqp, int* __restrict__ nn9) {
  int wg = blockIdx.x;                 // 800 = 8 xcd * 100
  int r = wg & 7, j = wg >> 3;
  int b  = r + 8 * (j / 25);
  int qt = j % 25;
  int q0 = qt * 32;
  int t = threadIdx.x, lane = t & 63, w = t >> 6;

  __shared__ unsigned int dkS[16][1028];  // 65.8 KB
  __shared__ float csqS[NP_];             // 4 KB
  __shared__ float qsqS[32];

  const float* sqb = sqp + (size_t)b * NP_;
  for (int i = t; i < NP_; i += 256) csqS[i] = sqb[i];
  if (t < 32) qsqS[t] = sqb[q0 + t];     // pad region defined (1e30)
  __syncthreads();

  const short8* fH = fragH + (size_t)b * 6 * 64 * 64;
  const short8* fL = fragL + (size_t)b * 6 * 64 * 64;

  int ga0 = qt * 2;
  int ga1 = qt * 2 + 1; if (ga1 > 48) ga1 = 48;   // tile 24: dup, discarded

  short8 aH0[6], aL0[6], aH1[6], aL1[6];
  #pragma unroll
  for (int ks = 0; ks < 6; ks++) {
    aH0[ks] = fH[((size_t)ks * 64 + ga0) * 64 + lane];
    aL0[ks] = fL[((size_t)ks * 64 + ga0) * 64 + lane];
    aH1[ks] = fH[((size_t)ks * 64 + ga1) * 64 + lane];
    aL1[ks] = fL[((size_t)ks * 64 + ga1) * 64 + lane];
  }

  int colL = lane & 15, rq = lane >> 4;
  unsigned int d1h[8][8];   // grp1 forded keys [iter][col0 rr0..3 | col1 rr0..3]

  #pragma unroll
  for (int it8 = 0; it8 < 8; it8++) {
    int g0 = w * 16 + it8 * 2, g1 = g0 + 1;
    f32x4 z = {0.f, 0.f, 0.f, 0.f};
    f32x4 c00h = z, c00l = z, c00x = z, c01h = z, c01l = z, c01x = z;
    f32x4 c10h = z, c10l = z, c10x = z, c11h = z, c11l = z, c11x = z;
    #pragma unroll
    for (int ks = 0; ks < 6; ks++) {
      short8 b0h = fH[((size_t)ks * 64 + g0) * 64 + lane];
      short8 b0l = fL[((size_t)ks * 64 + g0) * 64 + lane];
      short8 b1h = fH[((size_t)ks * 64 + g1) * 64 + lane];
      short8 b1l = fL[((size_t)ks * 64 + g1) * 64 + lane];
      c00h = __builtin_amdgcn_mfma_f32_16x16x32_bf16(aH0[ks], b0h, c00h, 0, 0, 0);
      c00l = __builtin_amdgcn_mfma_f32_16x16x32_bf16(aH0[ks], b0l, c00l, 0, 0, 0);
      c00x = __builtin_amdgcn_mfma_f32_16x16x32_bf16(aL0[ks], b0h, c00x, 0, 0, 0);
      c01h = __builtin_amdgcn_mfma_f32_16x16x32_bf16(aH0[ks], b1h, c01h, 0, 0, 0);
      c01l = __builtin_amdgcn_mfma_f32_16x16x32_bf16(aH0[ks], b1l, c01l, 0, 0, 0);
      c01x = __builtin_amdgcn_mfma_f32_16x16x32_bf16(aL0[ks], b1h, c01x, 0, 0, 0);
      c10h = __builtin_amdgcn_mfma_f32_16x16x32_bf16(aH1[ks], b0h, c10h, 0, 0, 0);
      c10l = __builtin_amdgcn_mfma_f32_16x16x32_bf16(aH1[ks], b0l, c10l, 0, 0, 0);
      c10x = __builtin_amdgcn_mfma_f32_16x16x32_bf16(aL1[ks], b0h, c10x, 0, 0, 0);
      c11h = __builtin_amdgcn_mfma_f32_16x16x32_bf16(aH1[ks], b1h, c11h, 0, 0, 0);
      c11l = __builtin_amdgcn_mfma_f32_16x16x32_bf16(aH1[ks], b1l, c11l, 0, 0, 0);
      c11x = __builtin_amdgcn_mfma_f32_16x16x32_bf16(aL1[ks], b1h, c11x, 0, 0, 0);
    }
    float cs0 = csqS[g0 * 16 + colL];
    float cs1 = csqS[g1 * 16 + colL];
    #pragma unroll
    for (int rr = 0; rr < 4; rr++) {
      int row = rq * 4 + rr;
      float qs0 = qsqS[row];
      float g0v = __fadd_rn(__fadd_rn(c00h[rr], c00l[rr]), c00x[rr]);
      float g1v = __fadd_rn(__fadd_rn(c01h[rr], c01l[rr]), c01x[rr]);
      dkS[row][g0 * 16 + colL] =
          ford(__fadd_rn(__fsub_rn(qs0, __fmul_rn(2.0f, g0v)), cs0));
      dkS[row][g1 * 16 + colL] =
          ford(__fadd_rn(__fsub_rn(qs0, __fmul_rn(2.0f, g1v)), cs1));
      float qs1 = qsqS[16 + row];
      float h0v = __fadd_rn(__fadd_rn(c10h[rr], c10l[rr]), c10x[rr]);
      float h1v = __fadd_rn(__fadd_rn(c11h[rr], c11l[rr]), c11x[rr]);
      d1h[it8][rr] =
          ford(__fadd_rn(__fsub_rn(qs1, __fmul_rn(2.0f, h0v)), cs0));
      d1h[it8][4 + rr] =
          ford(__fadd_rn(__fsub_rn(qs1, __fmul_rn(2.0f, h1v)), cs1));
    }
  }
  __syncthreads();

  // ---- selection pass 1: rows 0..15 (queries q0..q0+15, always valid) ----
  for (int s = 0; s < 4; s++) {
    int row = w * 4 + s;
    unsigned int bv = 0xFFFFFFFFu; int bi = lane;
    #pragma unroll
    for (int it = 0; it < 16; it++) {
      unsigned int k = dkS[row][lane + 64 * it];
      if (k < bv) { bv = k; bi = lane + 64 * it; }
    }
    int* o = nn9 + ((size_t)b * N_ + q0 + row) * K_;
    for (int kk = 0; kk < K_; kk++) {
      unsigned long long mk = ((unsigned long long)bv << 10) | (unsigned int)bi;
      #pragma unroll
      for (int off = 1; off < 64; off <<= 1) {
        unsigned long long v2 = __shfl_xor(mk, off);
        mk = v2 < mk ? v2 : mk;
      }
      int widx = (int)(mk & 1023u);
      if (lane == 0) o[kk] = widx;
      if ((widx & 63) == lane) {
        dkS[row][widx] = 0xFFFFFFFFu;
        bv = 0xFFFFFFFFu; bi = lane;
        #pragma unroll
        for (int it = 0; it < 16; it++) {
          unsigned int k = dkS[row][lane + 64 * it];
          if (k < bv) { bv = k; bi = lane + 64 * it; }
        }
      }
    }
  }
  __syncthreads();

  // ---- write grp1 keys, selection pass 2: rows 16..31 ----
  #pragma unroll
  for (int it8 = 0; it8 < 8; it8++) {
    int g0 = w * 16 + it8 * 2, g1 = g0 + 1;
    #pragma unroll
    for (int rr = 0; rr < 4; rr++) {
      dkS[rq * 4 + rr][g0 * 16 + colL] = d1h[it8][rr];
      dkS[rq * 4 + rr][g1 * 16 + colL] = d1h[it8][4 + rr];
    }
  }
  __syncthreads();

  for (int s = 0; s < 4; s++) {
    int row = w * 4 + s;
    int q = q0 + 16 + row;
    if (q >= N_) continue;             // tile 24 grp1 padding
    unsigned int bv = 0xFFFFFFFFu; int bi = lane;
    #pragma unroll
    for (int it = 0; it < 16; it++) {
      unsigned int k = dkS[row][lane + 64 * it];
      if (k < bv) { bv = k; bi = lane + 64 * it; }
    }
    int* o = nn9 + ((size_t)b * N_ + q) * K_;
    for (int kk = 0; kk < K_; kk++) {
      unsigned long long mk = ((unsigned long long)bv << 10) | (unsigned int)bi;
      #pragma unroll
      for (int off = 1; off < 64; off <<= 1) {
        unsigned long long v2 = __shfl_xor(mk, off);
        mk = v2 < mk ? v2 : mk;
      }
      int widx = (int)(mk & 1023u);
      if (lane == 0) o[kk] = widx;
      if ((widx & 63) == lane) {
        dkS[row][widx] = 0xFFFFFFFFu;
        bv = 0xFFFFFFFFu; bi = lane;
        #pragma unroll
        for (int it = 0; it < 16; it++) {
          unsigned int k = dkS[row][lane + 64 * it];
          if (k < bv) { bv = k; bi = lane + 64 * it; }
        }
      }
    }
  }
}

// ---------------------------------------------------------------------------
// K4: FUSED gather + max-relative + grouped 1x1 conv + BN partial sums.
// ---------------------------------------------------------------------------
__global__ __launch_bounds__(256) void fconv_kernel(
    const float* __restrict__ x, const int* __restrict__ nn9,
    const float* __restrict__ w, const float* __restrict__ bias,
    float* __restrict__ outpre, float* __restrict__ psum,
    float* __restrict__ pss) {
  int nt = blockIdx.x;
  int gh = blockIdx.y;
  int b  = blockIdx.z;
  int g = gh >> 1, half = gh & 1;
  int n0 = nt * 112;
  int t = threadIdx.x;

  __shared__ float Wl[48][97];
  __shared__ float Hl[96][112];
  __shared__ unsigned short Il[112][K_];

  const float* wsrc = w + (size_t)(g * 96 + half * 48) * 96;
  for (int i = t; i < 48 * 96; i += 256) Wl[i / 96][i % 96] = wsrc[i];
  const int* isrc = nn9 + ((size_t)b * N_ + n0) * K_;
  for (int i = t; i < 112 * K_; i += 256)
    Il[i / K_][i % K_] = (unsigned short)isrc[i];
  __syncthreads();

  const float* xb = x + (size_t)b * C_ * N_;
  for (int pos = t; pos < 48 * 112; pos += 256) {
    int cl = pos / 112, nl = pos % 112;
    const float* row = xb + (size_t)(g * 48 + cl) * N_;
    float xv = row[n0 + nl];
    float mx = -1e30f;
    #pragma unroll
    for (int k = 0; k < K_; k++) mx = fmaxf(mx, row[Il[nl][k]]);
    Hl[2 * cl][nl]     = xv;
    Hl[2 * cl + 1][nl] = mx - xv;
  }
  __syncthreads();

  int tx = t & 15, ty = t >> 4;
  float o[3][7];
  #pragma unroll
  for (int i = 0; i < 3; i++)
    #pragma unroll
    for (int j = 0; j < 7; j++) o[i][j] = 0.f;

  for (int k = 0; k < 96; k++) {
    float w0 = Wl[ty * 3 + 0][k];
    float w1 = Wl[ty * 3 + 1][k];
    float w2 = Wl[ty * 3 + 2][k];
    #pragma unroll
    for (int j = 0; j < 7; j++) {
      float hv = Hl[k][tx * 7 + j];
      o[0][j] = __fmaf_rn(w0, hv, o[0][j]);
      o[1][j] = __fmaf_rn(w1, hv, o[1][j]);
      o[2][j] = __fmaf_rn(w2, hv, o[2][j]);
    }
  }

  #pragma unroll
  for (int i = 0; i < 3; i++) {
    int co = g * 96 + half * 48 + ty * 3 + i;
    float bv = bias[co];
    float s = 0.f, s2 = 0.f;
    float* orow = outpre + ((size_t)b * COUT_ + co) * N_ + n0 + tx * 7;
    #pragma unroll
    for (int j = 0; j < 7; j++) {
      float v = o[i][j] + bv;
      orow[j] = v;
      s += v; s2 += v * v;
    }
    #pragma unroll
    for (int off = 1; off < 16; off <<= 1) {
      s  += __shfl_xor(s, off);
      s2 += __shfl_xor(s2, off);
    }
    if (tx == 0) {
      int tidx = b * 7 + nt;
      psum[co * NTILES_ + tidx] = s;
      pss [co * NTILES_ + tidx] = s2;
    }
  }
}

// ---------------------------------------------------------------------------
// K5: finalize BN stats -> per-channel affine a, b
// ---------------------------------------------------------------------------
__global__ __launch_bounds__(64) void stats_kernel(
    const float* __restrict__ psum, const float* __restrict__ pss,
    const float* __restrict__ gamma, const float* __restrict__ beta,
    float* __restrict__ af, float* __restrict__ bf) {
  int co = blockIdx.x;
  int l = threadIdx.x;
  double s = 0.0, s2 = 0.0;
  for (int i = l; i < NTILES_; i += 64) {
    s  += (double)psum[co * NTILES_ + i];
    s2 += (double)pss [co * NTILES_ + i];
  }
  #pragma unroll
  for (int o = 32; o > 0; o >>= 1) { s += __shfl_xor(s, o); s2 += __shfl_xor(s2, o); }
  if (l == 0) {
    const double cnt = (double)NPTS_;
    double mean = s / cnt;
    double var  = s2 / cnt - mean * mean;
    double rstd = 1.0 / sqrt(var + 1e-5);
    double a = (double)gamma[co] * rstd;
    af[co] = (float)a;
    bf[co] = (float)((double)beta[co] - mean * a);
  }
}

// ---------------------------------------------------------------------------
// K6: BN affine + exact GELU + fp32 store
// ---------------------------------------------------------------------------
__global__ __launch_bounds__(256) void act_kernel(
    const float* __restrict__ outpre, const float* __restrict__ af,
    const float* __restrict__ bf, float* __restrict__ out) {
  size_t i = ((size_t)blockIdx.x * 256 + threadIdx.x) * 4;
  int co = (int)((i / N_) % COUT_);
  float a = af[co], c = bf[co];
  float4 v = *(const float4*)(outpre + i);
  float y0 = a * v.x + c, y1 = a * v.y + c, y2 = a * v.z + c, y3 = a * v.w + c;
  const float is2 = 0.70710678118654752f;
  float4 r;
  r.x = 0.5f * y0 * (1.0f + erff(y0 * is2));
  r.y = 0.5f * y1 * (1.0f + erff(y1 * is2));
  r.z = 0.5f * y2 * (1.0f + erff(y2 * is2));
  r.w = 0.5f * y3 * (1.0f + erff(y3 * is2));
  *reinterpret_cast<float4*>(out + i) = r;
}

// ---------------------------------------------------------------------------
extern "C" void kernel_launch(void* const* d_in, const int* in_sizes, int n_in,
                              void* d_out, int out_size, void* d_ws, size_t ws_size,
                              hipStream_t stream) {
  const float* x      = (const float*)d_in[0];
  const float* conv_w = (const float*)d_in[1];
  const float* conv_b = (const float*)d_in[2];
  const float* gamma  = (const float*)d_in[3];
  const float* beta   = (const float*)d_in[4];
  float* out = (float*)d_out;

  float* buf0 = (float*)d_ws;
  float*  xnT   = buf0;
  float*  sqp   = buf0 + 6291456;
  short8* fragH = (short8*)(buf0 + 6324224);
  short8* fragL = (short8*)(buf0 + 9469952);
  int*    nn9   = (int*)(buf0 + 12615680);
  float*  psum  = buf0 + 12841472;
  float*  pss   = psum + COUT_ * NTILES_;
  float*  af    = pss + COUT_ * NTILES_;
  float*  bfv   = af + COUT_;
  float*  outpre = buf0;   // overlay [0, 9633792) — xnT dead after pack

  const int npad_total = B_ * C_ * (NP_ - N_) + B_ * (NP_ - N_);
  hipLaunchKernelGGL(pad_kernel, dim3((npad_total + 255) / 256), dim3(256), 0, stream,
                     xnT, sqp);
  hipLaunchKernelGGL(norm_kernel, dim3(NPTS_ / 64), dim3(256), 0, stream,
                     x, xnT, sqp);
  hipLaunchKernelGGL(pack_kernel, dim3(8, 6, B_), dim3(256), 0, stream,
                     xnT, fragH, fragL);
  hipLaunchKernelGGL(knn_kernel, dim3(25 * B_), dim3(256), 0, stream,
                     fragH, fragL, sqp, nn9);
  hipLaunchKernelGGL(fconv_kernel, dim3(7, 8, B_), dim3(256), 0, stream,
                     x, nn9, conv_w, conv_b, outpre, psum, pss);
  hipLaunchKernelGGL(stats_kernel, dim3(COUT_), dim3(64), 0, stream,
                     psum, pss, gamma, beta, af, bfv);
  hipLaunchKernelGGL(act_kernel, dim3((B_ * COUT_ * N_) / (256 * 4)), dim3(256), 0, stream,
                     outpre, af, bfv, out);
}

// Round 15
// 243.928 us; speedup vs baseline: 1.4198x; 1.4198x over previous
//
#include <hip/hip_runtime.h>

#define B_    32
#define C_    192
#define N_    784
#define NP_   1024        // padded candidate dim
#define K_    9
#define COUT_ 384
#define NPTS_ (B_ * N_)   // 25088
#define QPB_  16          // queries per knn block
#define NTILES_ 224       // 32 b * 7 ntiles

typedef __attribute__((ext_vector_type(8))) short short8;   // 8 bf16 = 4 VGPR
typedef __attribute__((ext_vector_type(4))) float f32x4;    // MFMA acc

// ordered-uint transform: monotone map float -> uint
__device__ __forceinline__ unsigned int ford(float f) {
  unsigned int u = __float_as_uint(f);
  return u ^ ((u & 0x80000000u) ? 0xFFFFFFFFu : 0x80000000u);
}
// fp32 -> bf16 (RNE) without library types
__device__ __forceinline__ unsigned short f2bf(float f) {
  unsigned int u = __float_as_uint(f);
  u += 0x7FFFu + ((u >> 16) & 1u);
  return (unsigned short)(u >> 16);
}
__device__ __forceinline__ float bf2f(unsigned short h) {
  return __uint_as_float(((unsigned int)h) << 16);
}

// ---------------------------------------------------------------------------
// K1: parallel norm. Block = 64 points x 4 c-groups. Writes xnT fp32 + sqp.
// ---------------------------------------------------------------------------
__global__ __launch_bounds__(256) void norm_kernel(
    const float* __restrict__ x, float* __restrict__ xnT,
    float* __restrict__ sqp) {
  int t = threadIdx.x;
  int pl = t & 63, cg = t >> 6;
  int p = blockIdx.x * 64 + pl;
  int b = p / N_, n = p % N_;
  const float* xb = x + (size_t)b * C_ * N_ + n;

  __shared__ float red[4][64];
  __shared__ float nrmS[64];

  float part = 0.f;
  #pragma unroll 8
  for (int j = 0; j < 48; j++) {
    float v = xb[(size_t)(cg * 48 + j) * N_];
    part = __fmaf_rn(v, v, part);
  }
  red[cg][pl] = part;
  __syncthreads();
  if (t < 64) {
    float ssq = __fadd_rn(__fadd_rn(red[0][t], red[1][t]),
                          __fadd_rn(red[2][t], red[3][t]));
    nrmS[t] = fmaxf(__fsqrt_rn(ssq), 1e-12f);
  }
  __syncthreads();
  float nrm = nrmS[pl];
  float* xt = xnT + (size_t)b * C_ * NP_ + n;
  float p2 = 0.f;
  #pragma unroll 8
  for (int j = 0; j < 48; j++) {
    float a = __fdiv_rn(xb[(size_t)(cg * 48 + j) * N_], nrm);
    xt[(size_t)(cg * 48 + j) * NP_] = a;
    p2 = __fmaf_rn(a, a, p2);
  }
  red[cg][pl] = p2;
  __syncthreads();
  if (t < 64) {
    float sq = __fadd_rn(__fadd_rn(red[0][t], red[1][t]),
                         __fadd_rn(red[2][t], red[3][t]));
    int pp = blockIdx.x * 64 + t;
    sqp[(size_t)(pp / N_) * NP_ + (pp % N_)] = sq;
  }
}

// ---------------------------------------------------------------------------
// K2: pack xnT into MFMA fragment buffers, split bf16 (hi, lo).
//  Pad columns (>= N_) are zero-filled in-flight (no pad kernel needed).
// ---------------------------------------------------------------------------
__global__ __launch_bounds__(256) void pack_kernel(
    const float* __restrict__ xnT, short8* __restrict__ fragH,
    short8* __restrict__ fragL) {
  int mc = blockIdx.x, ks = blockIdx.y, b = blockIdx.z;
  int t = threadIdx.x;
  __shared__ float T[32][133];

  const float* src = xnT + (size_t)b * C_ * NP_ + (size_t)(ks * 32) * NP_
                     + mc * 128;
  for (int i = t; i < 32 * 128; i += 256) {
    int col = mc * 128 + (i & 127);
    T[i >> 7][i & 127] =
        (col < N_) ? src[(size_t)(i >> 7) * NP_ + (i & 127)] : 0.f;
  }
  __syncthreads();

  for (int e = t; e < 512; e += 256) {
    int g = e >> 6, l = e & 63;
    int colL = l & 15, kq = l >> 4;
    union { short8 v; unsigned short u[8]; } ph, pl2;
    #pragma unroll
    for (int j = 0; j < 8; j++) {
      float v = T[kq * 8 + j][g * 16 + colL];
      unsigned short h = f2bf(v);
      ph.u[j]  = h;
      pl2.u[j] = f2bf(__fsub_rn(v, bf2f(h)));
    }
    size_t idx = (((size_t)b * 6 + ks) * 64 + (mc * 8 + g)) * 64 + l;
    fragH[idx] = ph.v;
    fragL[idx] = pl2.v;
  }
}

// ---------------------------------------------------------------------------
// K3: MFMA KNN (R13 structure, proven 134 us) + unroll-2 pipelining.
// ---------------------------------------------------------------------------
__global__ __launch_bounds__(256) void knn_kernel(
    const short8* __restrict__ fragH, const short8* __restrict__ fragL,
    const float* __restrict__ sqp, int* __restrict__ nn9) {
  int wg = blockIdx.x;
  int r = wg & 7, j = wg >> 3;
  int b  = r + 8 * (j / 49);
  int qt = j % 49;
  int q0 = qt * 16;
  int t = threadIdx.x, lane = t & 63, w = t >> 6;

  __shared__ unsigned int dkS[16][1028];  // 65.8 KB keys
  __shared__ float csqS[NP_];             // 4 KB
  __shared__ float qsqS[16];

  const float* sqb = sqp + (size_t)b * NP_;
  for (int i = t; i < NP_; i += 256)
    csqS[i] = (i < N_) ? sqb[i] : 1e30f;  // pad cols: +inf distance
  if (t < 16) qsqS[t] = sqb[q0 + t];
  __syncthreads();

  const short8* fH = fragH + (size_t)b * 6 * 64 * 64;
  const short8* fL = fragL + (size_t)b * 6 * 64 * 64;

  short8 aH[6], aL[6];
  #pragma unroll
  for (int ks = 0; ks < 6; ks++) {
    aH[ks] = fH[((size_t)ks * 64 + qt) * 64 + lane];
    aL[ks] = fL[((size_t)ks * 64 + qt) * 64 + lane];
  }

  int colL = lane & 15, rq = lane >> 4;

  #pragma unroll 2
  for (int gp = 0; gp < 16; gp += 2) {
    int g0 = w * 16 + gp, g1 = g0 + 1;
    f32x4 a00 = {0.f, 0.f, 0.f, 0.f}, a01 = a00, a02 = a00;
    f32x4 a10 = a00, a11 = a00, a12 = a00;
    #pragma unroll
    for (int ks = 0; ks < 6; ks++) {
      short8 b0h = fH[((size_t)ks * 64 + g0) * 64 + lane];
      short8 b0l = fL[((size_t)ks * 64 + g0) * 64 + lane];
      short8 b1h = fH[((size_t)ks * 64 + g1) * 64 + lane];
      short8 b1l = fL[((size_t)ks * 64 + g1) * 64 + lane];
      a00 = __builtin_amdgcn_mfma_f32_16x16x32_bf16(aH[ks], b0h, a00, 0, 0, 0);
      a01 = __builtin_amdgcn_mfma_f32_16x16x32_bf16(aH[ks], b0l, a01, 0, 0, 0);
      a02 = __builtin_amdgcn_mfma_f32_16x16x32_bf16(aL[ks], b0h, a02, 0, 0, 0);
      a10 = __builtin_amdgcn_mfma_f32_16x16x32_bf16(aH[ks], b1h, a10, 0, 0, 0);
      a11 = __builtin_amdgcn_mfma_f32_16x16x32_bf16(aH[ks], b1l, a11, 0, 0, 0);
      a12 = __builtin_amdgcn_mfma_f32_16x16x32_bf16(aL[ks], b1h, a12, 0, 0, 0);
    }
    float cs0 = csqS[g0 * 16 + colL];
    float cs1 = csqS[g1 * 16 + colL];
    #pragma unroll
    for (int rr = 0; rr < 4; rr++) {
      int row = rq * 4 + rr;
      float qs = qsqS[row];
      float g0v = __fadd_rn(__fadd_rn(a00[rr], a01[rr]), a02[rr]);
      float g1v = __fadd_rn(__fadd_rn(a10[rr], a11[rr]), a12[rr]);
      float d0 = __fadd_rn(__fsub_rn(qs, __fmul_rn(2.0f, g0v)), cs0);
      float d1 = __fadd_rn(__fsub_rn(qs, __fmul_rn(2.0f, g1v)), cs1);
      dkS[row][g0 * 16 + colL] = ford(d0);
      dkS[row][g1 * 16 + colL] = ford(d1);
    }
  }
  __syncthreads();

  for (int s = 0; s < 4; s++) {
    int row = w * 4 + s;
    unsigned int bv = 0xFFFFFFFFu; int bi = lane;
    #pragma unroll
    for (int it = 0; it < 16; it++) {
      unsigned int k = dkS[row][lane + 64 * it];
      if (k < bv) { bv = k; bi = lane + 64 * it; }
    }
    int* o = nn9 + ((size_t)b * N_ + q0 + row) * K_;
    for (int kk = 0; kk < K_; kk++) {
      unsigned long long mk = ((unsigned long long)bv << 10) | (unsigned int)bi;
      #pragma unroll
      for (int off = 1; off < 64; off <<= 1) {
        unsigned long long v2 = __shfl_xor(mk, off);
        mk = v2 < mk ? v2 : mk;
      }
      int widx = (int)(mk & 1023u);
      if (lane == 0) o[kk] = widx;
      if ((widx & 63) == lane) {
        dkS[row][widx] = 0xFFFFFFFFu;
        bv = 0xFFFFFFFFu; bi = lane;
        #pragma unroll
        for (int it = 0; it < 16; it++) {
          unsigned int k = dkS[row][lane + 64 * it];
          if (k < bv) { bv = k; bi = lane + 64 * it; }
        }
      }
    }
  }
}

// ---------------------------------------------------------------------------
// K4: FUSED gather + max-rel + grouped conv, BOTH halves per block
//  (Hl built once, Wl ping-pongs). grid = (7 nt, 4 g, 32 b), 256 thr.
// ---------------------------------------------------------------------------
__global__ __launch_bounds__(256) void fconv_kernel(
    const float* __restrict__ x, const int* __restrict__ nn9,
    const float* __restrict__ w, const float* __restrict__ bias,
    float* __restrict__ outpre, float* __restrict__ psum,
    float* __restrict__ pss) {
  int nt = blockIdx.x;
  int g  = blockIdx.y;
  int b  = blockIdx.z;
  int n0 = nt * 112;
  int t = threadIdx.x;

  __shared__ float Wl[48][97];            // 18.6 KB (ping-pong per half)
  __shared__ float Hl[96][112];           // 43.0 KB (shared by both halves)
  __shared__ unsigned short Il[112][K_];  // 2.0 KB

  const int* isrc = nn9 + ((size_t)b * N_ + n0) * K_;
  for (int i = t; i < 112 * K_; i += 256)
    Il[i / K_][i % K_] = (unsigned short)isrc[i];
  const float* wsrc0 = w + (size_t)(g * 96) * 96;
  for (int i = t; i < 48 * 96; i += 256) Wl[i / 96][i % 96] = wsrc0[i];
  __syncthreads();

  const float* xb = x + (size_t)b * C_ * N_;
  for (int pos = t; pos < 48 * 112; pos += 256) {
    int cl = pos / 112, nl = pos % 112;
    const float* row = xb + (size_t)(g * 48 + cl) * N_;
    float xv = row[n0 + nl];
    float mx = -1e30f;
    #pragma unroll
    for (int k = 0; k < K_; k++) mx = fmaxf(mx, row[Il[nl][k]]);
    Hl[2 * cl][nl]     = xv;
    Hl[2 * cl + 1][nl] = mx - xv;
  }
  __syncthreads();

  int tx = t & 15, ty = t >> 4;
  int tidx = b * 7 + nt;

  for (int half = 0; half < 2; half++) {
    float o[3][7];
    #pragma unroll
    for (int i = 0; i < 3; i++)
      #pragma unroll
      for (int j = 0; j < 7; j++) o[i][j] = 0.f;

    for (int k = 0; k < 96; k++) {
      float w0 = Wl[ty * 3 + 0][k];
      float w1 = Wl[ty * 3 + 1][k];
      float w2 = Wl[ty * 3 + 2][k];
      #pragma unroll
      for (int j = 0; j < 7; j++) {
        float hv = Hl[k][tx * 7 + j];
        o[0][j] = __fmaf_rn(w0, hv, o[0][j]);
        o[1][j] = __fmaf_rn(w1, hv, o[1][j]);
        o[2][j] = __fmaf_rn(w2, hv, o[2][j]);
      }
    }

    #pragma unroll
    for (int i = 0; i < 3; i++) {
      int co = g * 96 + half * 48 + ty * 3 + i;
      float bv = bias[co];
      float s = 0.f, s2 = 0.f;
      float* orow = outpre + ((size_t)b * COUT_ + co) * N_ + n0 + tx * 7;
      #pragma unroll
      for (int j = 0; j < 7; j++) {
        float v = o[i][j] + bv;
        orow[j] = v;
        s += v; s2 += v * v;
      }
      #pragma unroll
      for (int off = 1; off < 16; off <<= 1) {
        s  += __shfl_xor(s, off);
        s2 += __shfl_xor(s2, off);
      }
      if (tx == 0) {
        psum[co * NTILES_ + tidx] = s;
        pss [co * NTILES_ + tidx] = s2;
      }
    }

    if (half == 0) {
      __syncthreads();   // all GEMM reads of Wl done
      const float* wsrc1 = w + (size_t)(g * 96 + 48) * 96;
      for (int i = t; i < 48 * 96; i += 256) Wl[i / 96][i % 96] = wsrc1[i];
      __syncthreads();
    }
  }
}

// ---------------------------------------------------------------------------
// K5: finalize BN stats -> per-channel affine a, b
// ---------------------------------------------------------------------------
__global__ __launch_bounds__(64) void stats_kernel(
    const float* __restrict__ psum, const float* __restrict__ pss,
    const float* __restrict__ gamma, const float* __restrict__ beta,
    float* __restrict__ af, float* __restrict__ bf) {
  int co = blockIdx.x;
  int l = threadIdx.x;
  double s = 0.0, s2 = 0.0;
  for (int i = l; i < NTILES_; i += 64) {
    s  += (double)psum[co * NTILES_ + i];
    s2 += (double)pss [co * NTILES_ + i];
  }
  #pragma unroll
  for (int o = 32; o > 0; o >>= 1) { s += __shfl_xor(s, o); s2 += __shfl_xor(s2, o); }
  if (l == 0) {
    const double cnt = (double)NPTS_;
    double mean = s / cnt;
    double var  = s2 / cnt - mean * mean;
    double rstd = 1.0 / sqrt(var + 1e-5);
    double a = (double)gamma[co] * rstd;
    af[co] = (float)a;
    bf[co] = (float)((double)beta[co] - mean * a);
  }
}

// ---------------------------------------------------------------------------
// K6: BN affine + exact GELU + fp32 store
// ---------------------------------------------------------------------------
__global__ __launch_bounds__(256) void act_kernel(
    const float* __restrict__ outpre, const float* __restrict__ af,
    const float* __restrict__ bf, float* __restrict__ out) {
  size_t i = ((size_t)blockIdx.x * 256 + threadIdx.x) * 4;
  int co = (int)((i / N_) % COUT_);
  float a = af[co], c = bf[co];
  float4 v = *(const float4*)(outpre + i);
  float y0 = a * v.x + c, y1 = a * v.y + c, y2 = a * v.z + c, y3 = a * v.w + c;
  const float is2 = 0.70710678118654752f;
  float4 r;
  r.x = 0.5f * y0 * (1.0f + erff(y0 * is2));
  r.y = 0.5f * y1 * (1.0f + erff(y1 * is2));
  r.z = 0.5f * y2 * (1.0f + erff(y2 * is2));
  r.w = 0.5f * y3 * (1.0f + erff(y3 * is2));
  *reinterpret_cast<float4*>(out + i) = r;
}

// ---------------------------------------------------------------------------
extern "C" void kernel_launch(void* const* d_in, const int* in_sizes, int n_in,
                              void* d_out, int out_size, void* d_ws, size_t ws_size,
                              hipStream_t stream) {
  const float* x      = (const float*)d_in[0];
  const float* conv_w = (const float*)d_in[1];
  const float* conv_b = (const float*)d_in[2];
  const float* gamma  = (const float*)d_in[3];
  const float* beta   = (const float*)d_in[4];
  float* out = (float*)d_out;

  float* buf0 = (float*)d_ws;
  float*  xnT   = buf0;
  float*  sqp   = buf0 + 6291456;
  short8* fragH = (short8*)(buf0 + 6324224);
  short8* fragL = (short8*)(buf0 + 9469952);
  int*    nn9   = (int*)(buf0 + 12615680);
  float*  psum  = buf0 + 12841472;
  float*  pss   = psum + COUT_ * NTILES_;
  float*  af    = pss + COUT_ * NTILES_;
  float*  bfv   = af + COUT_;
  float*  outpre = buf0;   // overlay [0, 9633792) — xnT dead after pack

  hipLaunchKernelGGL(norm_kernel, dim3(NPTS_ / 64), dim3(256), 0, stream,
                     x, xnT, sqp);
  hipLaunchKernelGGL(pack_kernel, dim3(8, 6, B_), dim3(256), 0, stream,
                     xnT, fragH, fragL);
  hipLaunchKernelGGL(knn_kernel, dim3(49 * B_), dim3(256), 0, stream,
                     fragH, fragL, sqp, nn9);
  hipLaunchKernelGGL(fconv_kernel, dim3(7, 4, B_), dim3(256), 0, stream,
                     x, nn9, conv_w, conv_b, outpre, psum, pss);
  hipLaunchKernelGGL(stats_kernel, dim3(COUT_), dim3(64), 0, stream,
                     psum, pss, gamma, beta, af, bfv);
  hipLaunchKernelGGL(act_kernel, dim3((B_ * COUT_ * N_) / (256 * 4)), dim3(256), 0, stream,
                     outpre, af, bfv, out);
}

// Round 17
// 243.837 us; speedup vs baseline: 1.4204x; 1.0004x over previous
//
#include <hip/hip_runtime.h>

#define B_    32
#define C_    192
#define N_    784
#define NP_   1024        // sqp row stride (pad never read)
#define K_    9
#define COUT_ 384
#define NPTS_ (B_ * N_)   // 25088
#define NTILES_ 224       // 32 b * 7 ntiles

typedef __attribute__((ext_vector_type(8))) short short8;   // 8 bf16 = 4 VGPR
typedef __attribute__((ext_vector_type(4))) float f32x4;    // MFMA acc

// ordered-uint transform: monotone map float -> uint
__device__ __forceinline__ unsigned int ford(float f) {
  unsigned int u = __float_as_uint(f);
  return u ^ ((u & 0x80000000u) ? 0xFFFFFFFFu : 0x80000000u);
}
// fp32 -> bf16 (RNE)
__device__ __forceinline__ unsigned short f2bf(float f) {
  unsigned int u = __float_as_uint(f);
  u += 0x7FFFu + ((u >> 16) & 1u);
  return (unsigned short)(u >> 16);
}
__device__ __forceinline__ float bf2f(unsigned short h) {
  return __uint_as_float(((unsigned int)h) << 16);
}

// ---------------------------------------------------------------------------
// K0: zero the pad fragment groups g in [49,64) (knn reads them; they must
// be deterministic finite values -> distances ~1e30, never selected).
// 184320 = 32 b * 6 ks * 15 g * 64 lanes.
// ---------------------------------------------------------------------------
__global__ __launch_bounds__(256) void padfrag_kernel(
    short8* __restrict__ fragH, short8* __restrict__ fragL) {
  int i = blockIdx.x * 256 + threadIdx.x;
  if (i >= 184320) return;
  int lane = i & 63;
  int rest = i >> 6;                 // [0, 2880)
  int g  = 49 + (rest % 15);
  int ks = (rest / 15) % 6;
  int b  = rest / 90;
  size_t idx = (((size_t)b * 6 + ks) * 64 + g) * 64 + lane;
  short8 z = {0, 0, 0, 0, 0, 0, 0, 0};
  fragH[idx] = z;
  fragL[idx] = z;
}

// ---------------------------------------------------------------------------
// K1: norm + FUSED frag pack (bit-exact vs R13 pack layout, verified on
// concrete elements). Block = 64 points x 4 c-groups (256 thr).
// ---------------------------------------------------------------------------
__global__ __launch_bounds__(256) void norm_kernel(
    const float* __restrict__ x, short8* __restrict__ fragH,
    short8* __restrict__ fragL, float* __restrict__ sqp) {
  int t = threadIdx.x;
  int pl = t & 63, cg = t >> 6;
  int p = blockIdx.x * 64 + pl;
  int b = p / N_, n = p % N_;
  const float* xb = x + (size_t)b * C_ * N_ + n;

  __shared__ float red[4][64];
  __shared__ float nrmS[64];

  float part = 0.f;
  #pragma unroll 8
  for (int j = 0; j < 48; j++) {
    float v = xb[(size_t)(cg * 48 + j) * N_];
    part = __fmaf_rn(v, v, part);
  }
  red[cg][pl] = part;
  __syncthreads();
  if (t < 64) {
    float ssq = __fadd_rn(__fadd_rn(red[0][t], red[1][t]),
                          __fadd_rn(red[2][t], red[3][t]));
    nrmS[t] = fmaxf(__fsqrt_rn(ssq), 1e-12f);
  }
  __syncthreads();
  float nrm = nrmS[pl];
  int g = n >> 4, li = n & 15;
  float p2 = 0.f;
  #pragma unroll
  for (int s = 0; s < 6; s++) {
    int kslot = cg * 6 + s;          // 0..23
    int ks = kslot >> 2, kq = kslot & 3;
    union { short8 v; unsigned short u[8]; } ph, plo;
    #pragma unroll
    for (int j = 0; j < 8; j++) {
      float a = __fdiv_rn(xb[(size_t)(kslot * 8 + j) * N_], nrm);
      unsigned short h = f2bf(a);
      ph.u[j]  = h;
      plo.u[j] = f2bf(__fsub_rn(a, bf2f(h)));
      p2 = __fmaf_rn(a, a, p2);
    }
    size_t idx = (((size_t)b * 6 + ks) * 64 + g) * 64 + (kq * 16 + li);
    fragH[idx] = ph.v;
    fragL[idx] = plo.v;
  }
  red[cg][pl] = p2;
  __syncthreads();
  if (t < 64) {
    float sq = __fadd_rn(__fadd_rn(red[0][t], red[1][t]),
                         __fadd_rn(red[2][t], red[3][t]));
    int pp = blockIdx.x * 64 + t;
    sqp[(size_t)(pp / N_) * NP_ + (pp % N_)] = sq;
  }
}

// ---------------------------------------------------------------------------
// K2: MFMA KNN — R15 structure VERBATIM (proven 132.5 us, passing).
// ---------------------------------------------------------------------------
__global__ __launch_bounds__(256) void knn_kernel(
    const short8* __restrict__ fragH, const short8* __restrict__ fragL,
    const float* __restrict__ sqp, int* __restrict__ nn9) {
  int wg = blockIdx.x;
  int r = wg & 7, j = wg >> 3;
  int b  = r + 8 * (j / 49);
  int qt = j % 49;
  int q0 = qt * 16;
  int t = threadIdx.x, lane = t & 63, w = t >> 6;

  __shared__ unsigned int dkS[16][1028];  // 65.8 KB keys
  __shared__ float csqS[NP_];             // 4 KB
  __shared__ float qsqS[16];

  const float* sqb = sqp + (size_t)b * NP_;
  for (int i = t; i < NP_; i += 256)
    csqS[i] = (i < N_) ? sqb[i] : 1e30f;  // pad cols: +inf distance
  if (t < 16) qsqS[t] = sqb[q0 + t];
  __syncthreads();

  const short8* fH = fragH + (size_t)b * 6 * 64 * 64;
  const short8* fL = fragL + (size_t)b * 6 * 64 * 64;

  short8 aH[6], aL[6];
  #pragma unroll
  for (int ks = 0; ks < 6; ks++) {
    aH[ks] = fH[((size_t)ks * 64 + qt) * 64 + lane];
    aL[ks] = fL[((size_t)ks * 64 + qt) * 64 + lane];
  }

  int colL = lane & 15, rq = lane >> 4;

  #pragma unroll 2
  for (int gp = 0; gp < 16; gp += 2) {
    int g0 = w * 16 + gp, g1 = g0 + 1;
    f32x4 a00 = {0.f, 0.f, 0.f, 0.f}, a01 = a00, a02 = a00;
    f32x4 a10 = a00, a11 = a00, a12 = a00;
    #pragma unroll
    for (int ks = 0; ks < 6; ks++) {
      short8 b0h = fH[((size_t)ks * 64 + g0) * 64 + lane];
      short8 b0l = fL[((size_t)ks * 64 + g0) * 64 + lane];
      short8 b1h = fH[((size_t)ks * 64 + g1) * 64 + lane];
      short8 b1l = fL[((size_t)ks * 64 + g1) * 64 + lane];
      a00 = __builtin_amdgcn_mfma_f32_16x16x32_bf16(aH[ks], b0h, a00, 0, 0, 0);
      a01 = __builtin_amdgcn_mfma_f32_16x16x32_bf16(aH[ks], b0l, a01, 0, 0, 0);
      a02 = __builtin_amdgcn_mfma_f32_16x16x32_bf16(aL[ks], b0h, a02, 0, 0, 0);
      a10 = __builtin_amdgcn_mfma_f32_16x16x32_bf16(aH[ks], b1h, a10, 0, 0, 0);
      a11 = __builtin_amdgcn_mfma_f32_16x16x32_bf16(aH[ks], b1l, a11, 0, 0, 0);
      a12 = __builtin_amdgcn_mfma_f32_16x16x32_bf16(aL[ks], b1h, a12, 0, 0, 0);
    }
    float cs0 = csqS[g0 * 16 + colL];
    float cs1 = csqS[g1 * 16 + colL];
    #pragma unroll
    for (int rr = 0; rr < 4; rr++) {
      int row = rq * 4 + rr;
      float qs = qsqS[row];
      float g0v = __fadd_rn(__fadd_rn(a00[rr], a01[rr]), a02[rr]);
      float g1v = __fadd_rn(__fadd_rn(a10[rr], a11[rr]), a12[rr]);
      float d0 = __fadd_rn(__fsub_rn(qs, __fmul_rn(2.0f, g0v)), cs0);
      float d1 = __fadd_rn(__fsub_rn(qs, __fmul_rn(2.0f, g1v)), cs1);
      dkS[row][g0 * 16 + colL] = ford(d0);
      dkS[row][g1 * 16 + colL] = ford(d1);
    }
  }
  __syncthreads();

  for (int s = 0; s < 4; s++) {
    int row = w * 4 + s;
    unsigned int bv = 0xFFFFFFFFu; int bi = lane;
    #pragma unroll
    for (int it = 0; it < 16; it++) {
      unsigned int k = dkS[row][lane + 64 * it];
      if (k < bv) { bv = k; bi = lane + 64 * it; }
    }
    int* o = nn9 + ((size_t)b * N_ + q0 + row) * K_;
    for (int kk = 0; kk < K_; kk++) {
      unsigned long long mk = ((unsigned long long)bv << 10) | (unsigned int)bi;
      #pragma unroll
      for (int off = 1; off < 64; off <<= 1) {
        unsigned long long v2 = __shfl_xor(mk, off);
        mk = v2 < mk ? v2 : mk;
      }
      int widx = (int)(mk & 1023u);
      if (lane == 0) o[kk] = widx;
      if ((widx & 63) == lane) {
        dkS[row][widx] = 0xFFFFFFFFu;
        bv = 0xFFFFFFFFu; bi = lane;
        #pragma unroll
        for (int it = 0; it < 16; it++) {
          unsigned int k = dkS[row][lane + 64 * it];
          if (k < bv) { bv = k; bi = lane + 64 * it; }
        }
      }
    }
  }
}

// ---------------------------------------------------------------------------
// K3: FUSED gather + max-rel + grouped conv, both halves per block (R15).
// ---------------------------------------------------------------------------
__global__ __launch_bounds__(256) void fconv_kernel(
    const float* __restrict__ x, const int* __restrict__ nn9,
    const float* __restrict__ w, const float* __restrict__ bias,
    float* __restrict__ outpre, float* __restrict__ psum,
    float* __restrict__ pss) {
  int nt = blockIdx.x;
  int g  = blockIdx.y;
  int b  = blockIdx.z;
  int n0 = nt * 112;
  int t = threadIdx.x;

  __shared__ float Wl[48][97];
  __shared__ float Hl[96][112];
  __shared__ unsigned short Il[112][K_];

  const int* isrc = nn9 + ((size_t)b * N_ + n0) * K_;
  for (int i = t; i < 112 * K_; i += 256)
    Il[i / K_][i % K_] = (unsigned short)isrc[i];
  const float* wsrc0 = w + (size_t)(g * 96) * 96;
  for (int i = t; i < 48 * 96; i += 256) Wl[i / 96][i % 96] = wsrc0[i];
  __syncthreads();

  const float* xb = x + (size_t)b * C_ * N_;
  for (int pos = t; pos < 48 * 112; pos += 256) {
    int cl = pos / 112, nl = pos % 112;
    const float* row = xb + (size_t)(g * 48 + cl) * N_;
    float xv = row[n0 + nl];
    float mx = -1e30f;
    #pragma unroll
    for (int k = 0; k < K_; k++) mx = fmaxf(mx, row[Il[nl][k]]);
    Hl[2 * cl][nl]     = xv;
    Hl[2 * cl + 1][nl] = mx - xv;
  }
  __syncthreads();

  int tx = t & 15, ty = t >> 4;
  int tidx = b * 7 + nt;

  for (int half = 0; half < 2; half++) {
    float o[3][7];
    #pragma unroll
    for (int i = 0; i < 3; i++)
      #pragma unroll
      for (int j = 0; j < 7; j++) o[i][j] = 0.f;

    for (int k = 0; k < 96; k++) {
      float w0 = Wl[ty * 3 + 0][k];
      float w1 = Wl[ty * 3 + 1][k];
      float w2 = Wl[ty * 3 + 2][k];
      #pragma unroll
      for (int j = 0; j < 7; j++) {
        float hv = Hl[k][tx * 7 + j];
        o[0][j] = __fmaf_rn(w0, hv, o[0][j]);
        o[1][j] = __fmaf_rn(w1, hv, o[1][j]);
        o[2][j] = __fmaf_rn(w2, hv, o[2][j]);
      }
    }

    #pragma unroll
    for (int i = 0; i < 3; i++) {
      int co = g * 96 + half * 48 + ty * 3 + i;
      float bv = bias[co];
      float s = 0.f, s2 = 0.f;
      float* orow = outpre + ((size_t)b * COUT_ + co) * N_ + n0 + tx * 7;
      #pragma unroll
      for (int j = 0; j < 7; j++) {
        float v = o[i][j] + bv;
        orow[j] = v;
        s += v; s2 += v * v;
      }
      #pragma unroll
      for (int off = 1; off < 16; off <<= 1) {
        s  += __shfl_xor(s, off);
        s2 += __shfl_xor(s2, off);
      }
      if (tx == 0) {
        psum[co * NTILES_ + tidx] = s;
        pss [co * NTILES_ + tidx] = s2;
      }
    }

    if (half == 0) {
      __syncthreads();
      const float* wsrc1 = w + (size_t)(g * 96 + 48) * 96;
      for (int i = t; i < 48 * 96; i += 256) Wl[i / 96][i % 96] = wsrc1[i];
      __syncthreads();
    }
  }
}

// ---------------------------------------------------------------------------
// K4: finalize BN stats -> per-channel affine a, b
// ---------------------------------------------------------------------------
__global__ __launch_bounds__(64) void stats_kernel(
    const float* __restrict__ psum, const float* __restrict__ pss,
    const float* __restrict__ gamma, const float* __restrict__ beta,
    float* __restrict__ af, float* __restrict__ bf) {
  int co = blockIdx.x;
  int l = threadIdx.x;
  double s = 0.0, s2 = 0.0;
  for (int i = l; i < NTILES_; i += 64) {
    s  += (double)psum[co * NTILES_ + i];
    s2 += (double)pss [co * NTILES_ + i];
  }
  #pragma unroll
  for (int o = 32; o > 0; o >>= 1) { s += __shfl_xor(s, o); s2 += __shfl_xor(s2, o); }
  if (l == 0) {
    const double cnt = (double)NPTS_;
    double mean = s / cnt;
    double var  = s2 / cnt - mean * mean;
    double rstd = 1.0 / sqrt(var + 1e-5);
    double a = (double)gamma[co] * rstd;
    af[co] = (float)a;
    bf[co] = (float)((double)beta[co] - mean * a);
  }
}

// ---------------------------------------------------------------------------
// K5: BN affine + exact GELU + fp32 store
// ---------------------------------------------------------------------------
__global__ __launch_bounds__(256) void act_kernel(
    const float* __restrict__ outpre, const float* __restrict__ af,
    const float* __restrict__ bf, float* __restrict__ out) {
  size_t i = ((size_t)blockIdx.x * 256 + threadIdx.x) * 4;
  int co = (int)((i / N_) % COUT_);
  float a = af[co], c = bf[co];
  float4 v = *(const float4*)(outpre + i);
  float y0 = a * v.x + c, y1 = a * v.y + c, y2 = a * v.z + c, y3 = a * v.w + c;
  const float is2 = 0.70710678118654752f;
  float4 r;
  r.x = 0.5f * y0 * (1.0f + erff(y0 * is2));
  r.y = 0.5f * y1 * (1.0f + erff(y1 * is2));
  r.z = 0.5f * y2 * (1.0f + erff(y2 * is2));
  r.w = 0.5f * y3 * (1.0f + erff(y3 * is2));
  *reinterpret_cast<float4*>(out + i) = r;
}

// ---------------------------------------------------------------------------
extern "C" void kernel_launch(void* const* d_in, const int* in_sizes, int n_in,
                              void* d_out, int out_size, void* d_ws, size_t ws_size,
                              hipStream_t stream) {
  const float* x      = (const float*)d_in[0];
  const float* conv_w = (const float*)d_in[1];
  const float* conv_b = (const float*)d_in[2];
  const float* gamma  = (const float*)d_in[3];
  const float* beta   = (const float*)d_in[4];
  float* out = (float*)d_out;

  // ws layout (float offsets), ~65 MB:
  float* buf0 = (float*)d_ws;
  short8* fragH = (short8*)buf0;                         // [0, 3145728)
  short8* fragL = (short8*)(buf0 + 3145728);             // [3145728, 6291456)
  float*  sqp   = buf0 + 6291456;                        // [6291456, 6324224)
  int*    nn9   = (int*)(buf0 + 6324224);                // [6324224, 6550016)
  float*  outpre = buf0 + 6550016;                       // [6550016, 16183808)
  float*  psum  = buf0 + 16183808;
  float*  pss   = psum + COUT_ * NTILES_;
  float*  af    = pss + COUT_ * NTILES_;
  float*  bfv   = af + COUT_;

  hipLaunchKernelGGL(padfrag_kernel, dim3(720), dim3(256), 0, stream,
                     fragH, fragL);
  hipLaunchKernelGGL(norm_kernel, dim3(NPTS_ / 64), dim3(256), 0, stream,
                     x, fragH, fragL, sqp);
  hipLaunchKernelGGL(knn_kernel, dim3(49 * B_), dim3(256), 0, stream,
                     fragH, fragL, sqp, nn9);
  hipLaunchKernelGGL(fconv_kernel, dim3(7, 4, B_), dim3(256), 0, stream,
                     x, nn9, conv_w, conv_b, outpre, psum, pss);
  hipLaunchKernelGGL(stats_kernel, dim3(COUT_), dim3(64), 0, stream,
                     psum, pss, gamma, beta, af, bfv);
  hipLaunchKernelGGL(act_kernel, dim3((B_ * COUT_ * N_) / (256 * 4)), dim3(256), 0, stream,
                     outpre, af, bfv, out);
}

// Round 18
// 243.161 us; speedup vs baseline: 1.4243x; 1.0028x over previous
//
#include <hip/hip_runtime.h>

#define B_    32
#define C_    192
#define N_    784
#define NP_   1024        // sqp row stride (pad never read)
#define K_    9
#define COUT_ 384
#define NPTS_ (B_ * N_)   // 25088
#define NTILES_ 224       // 32 b * 7 ntiles

typedef __attribute__((ext_vector_type(8))) short short8;   // 8 bf16 = 4 VGPR
typedef __attribute__((ext_vector_type(4))) float f32x4;    // MFMA acc

// ordered-uint transform: monotone map float -> uint
__device__ __forceinline__ unsigned int ford(float f) {
  unsigned int u = __float_as_uint(f);
  return u ^ ((u & 0x80000000u) ? 0xFFFFFFFFu : 0x80000000u);
}
// fp32 -> bf16 (RNE)
__device__ __forceinline__ unsigned short f2bf(float f) {
  unsigned int u = __float_as_uint(f);
  u += 0x7FFFu + ((u >> 16) & 1u);
  return (unsigned short)(u >> 16);
}
__device__ __forceinline__ float bf2f(unsigned short h) {
  return __uint_as_float(((unsigned int)h) << 16);
}

// ---------------------------------------------------------------------------
// K0: zero the pad fragment groups g in [49,64) (knn reads them; must be
// deterministic finite -> distance ~1e30, never selected).
// ---------------------------------------------------------------------------
__global__ __launch_bounds__(256) void padfrag_kernel(
    short8* __restrict__ fragH, short8* __restrict__ fragL) {
  int i = blockIdx.x * 256 + threadIdx.x;
  if (i >= 184320) return;
  int lane = i & 63;
  int rest = i >> 6;                 // [0, 2880)
  int g  = 49 + (rest % 15);
  int ks = (rest / 15) % 6;
  int b  = rest / 90;
  size_t idx = (((size_t)b * 6 + ks) * 64 + g) * 64 + lane;
  short8 z = {0, 0, 0, 0, 0, 0, 0, 0};
  fragH[idx] = z;
  fragL[idx] = z;
}

// ---------------------------------------------------------------------------
// K1: norm + FUSED frag pack (proven R17). Block = 64 pts x 4 c-groups.
// ---------------------------------------------------------------------------
__global__ __launch_bounds__(256) void norm_kernel(
    const float* __restrict__ x, short8* __restrict__ fragH,
    short8* __restrict__ fragL, float* __restrict__ sqp) {
  int t = threadIdx.x;
  int pl = t & 63, cg = t >> 6;
  int p = blockIdx.x * 64 + pl;
  int b = p / N_, n = p % N_;
  const float* xb = x + (size_t)b * C_ * N_ + n;

  __shared__ float red[4][64];
  __shared__ float nrmS[64];

  float part = 0.f;
  #pragma unroll 8
  for (int j = 0; j < 48; j++) {
    float v = xb[(size_t)(cg * 48 + j) * N_];
    part = __fmaf_rn(v, v, part);
  }
  red[cg][pl] = part;
  __syncthreads();
  if (t < 64) {
    float ssq = __fadd_rn(__fadd_rn(red[0][t], red[1][t]),
                          __fadd_rn(red[2][t], red[3][t]));
    nrmS[t] = fmaxf(__fsqrt_rn(ssq), 1e-12f);
  }
  __syncthreads();
  float nrm = nrmS[pl];
  int g = n >> 4, li = n & 15;
  float p2 = 0.f;
  #pragma unroll
  for (int s = 0; s < 6; s++) {
    int kslot = cg * 6 + s;          // 0..23
    int ks = kslot >> 2, kq = kslot & 3;
    union { short8 v; unsigned short u[8]; } ph, plo;
    #pragma unroll
    for (int j = 0; j < 8; j++) {
      float a = __fdiv_rn(xb[(size_t)(kslot * 8 + j) * N_], nrm);
      unsigned short h = f2bf(a);
      ph.u[j]  = h;
      plo.u[j] = f2bf(__fsub_rn(a, bf2f(h)));
      p2 = __fmaf_rn(a, a, p2);
    }
    size_t idx = (((size_t)b * 6 + ks) * 64 + g) * 64 + (kq * 16 + li);
    fragH[idx] = ph.v;
    fragL[idx] = plo.v;
  }
  red[cg][pl] = p2;
  __syncthreads();
  if (t < 64) {
    float sq = __fadd_rn(__fadd_rn(red[0][t], red[1][t]),
                         __fadd_rn(red[2][t], red[3][t]));
    int pp = blockIdx.x * 64 + t;
    sqp[(size_t)(pp / N_) * NP_ + (pp % N_)] = sq;
  }
}

// ---------------------------------------------------------------------------
// K2: MFMA KNN — 512 threads (8 waves) per block for 4 waves/SIMD.
//  Wave w computes groups w*8 .. w*8+7 (4 pair-iters); selects rows
//  w*2, w*2+1. Same dkS layout / strip-scan / knockout as R17 (proven).
//  Per-accumulator MFMA chains bit-identical to R17.
// ---------------------------------------------------------------------------
__global__ __launch_bounds__(512) void knn_kernel(
    const short8* __restrict__ fragH, const short8* __restrict__ fragL,
    const float* __restrict__ sqp, int* __restrict__ nn9) {
  int wg = blockIdx.x;
  int r = wg & 7, j = wg >> 3;
  int b  = r + 8 * (j / 49);
  int qt = j % 49;
  int q0 = qt * 16;
  int t = threadIdx.x, lane = t & 63, w = t >> 6;   // w in [0,8)

  __shared__ unsigned int dkS[16][1028];  // 65.8 KB keys
  __shared__ float csqS[NP_];             // 4 KB
  __shared__ float qsqS[16];

  const float* sqb = sqp + (size_t)b * NP_;
  for (int i = t; i < NP_; i += 512)
    csqS[i] = (i < N_) ? sqb[i] : 1e30f;  // pad cols: huge distance
  if (t < 16) qsqS[t] = sqb[q0 + t];
  __syncthreads();

  const short8* fH = fragH + (size_t)b * 6 * 64 * 64;
  const short8* fL = fragL + (size_t)b * 6 * 64 * 64;

  short8 aH[6], aL[6];
  #pragma unroll
  for (int ks = 0; ks < 6; ks++) {
    aH[ks] = fH[((size_t)ks * 64 + qt) * 64 + lane];
    aL[ks] = fL[((size_t)ks * 64 + qt) * 64 + lane];
  }

  int colL = lane & 15, rq = lane >> 4;

  #pragma unroll 2
  for (int gp = 0; gp < 8; gp += 2) {
    int g0 = w * 8 + gp, g1 = g0 + 1;
    f32x4 a00 = {0.f, 0.f, 0.f, 0.f}, a01 = a00, a02 = a00;
    f32x4 a10 = a00, a11 = a00, a12 = a00;
    #pragma unroll
    for (int ks = 0; ks < 6; ks++) {
      short8 b0h = fH[((size_t)ks * 64 + g0) * 64 + lane];
      short8 b0l = fL[((size_t)ks * 64 + g0) * 64 + lane];
      short8 b1h = fH[((size_t)ks * 64 + g1) * 64 + lane];
      short8 b1l = fL[((size_t)ks * 64 + g1) * 64 + lane];
      a00 = __builtin_amdgcn_mfma_f32_16x16x32_bf16(aH[ks], b0h, a00, 0, 0, 0);
      a01 = __builtin_amdgcn_mfma_f32_16x16x32_bf16(aH[ks], b0l, a01, 0, 0, 0);
      a02 = __builtin_amdgcn_mfma_f32_16x16x32_bf16(aL[ks], b0h, a02, 0, 0, 0);
      a10 = __builtin_amdgcn_mfma_f32_16x16x32_bf16(aH[ks], b1h, a10, 0, 0, 0);
      a11 = __builtin_amdgcn_mfma_f32_16x16x32_bf16(aH[ks], b1l, a11, 0, 0, 0);
      a12 = __builtin_amdgcn_mfma_f32_16x16x32_bf16(aL[ks], b1h, a12, 0, 0, 0);
    }
    float cs0 = csqS[g0 * 16 + colL];
    float cs1 = csqS[g1 * 16 + colL];
    #pragma unroll
    for (int rr = 0; rr < 4; rr++) {
      int row = rq * 4 + rr;
      float qs = qsqS[row];
      float g0v = __fadd_rn(__fadd_rn(a00[rr], a01[rr]), a02[rr]);
      float g1v = __fadd_rn(__fadd_rn(a10[rr], a11[rr]), a12[rr]);
      float d0 = __fadd_rn(__fsub_rn(qs, __fmul_rn(2.0f, g0v)), cs0);
      float d1 = __fadd_rn(__fsub_rn(qs, __fmul_rn(2.0f, g1v)), cs1);
      dkS[row][g0 * 16 + colL] = ford(d0);
      dkS[row][g1 * 16 + colL] = ford(d1);
    }
  }
  __syncthreads();

  for (int s = 0; s < 2; s++) {
    int row = w * 2 + s;
    unsigned int bv = 0xFFFFFFFFu; int bi = lane;
    #pragma unroll
    for (int it = 0; it < 16; it++) {
      unsigned int k = dkS[row][lane + 64 * it];
      if (k < bv) { bv = k; bi = lane + 64 * it; }
    }
    int* o = nn9 + ((size_t)b * N_ + q0 + row) * K_;
    for (int kk = 0; kk < K_; kk++) {
      unsigned long long mk = ((unsigned long long)bv << 10) | (unsigned int)bi;
      #pragma unroll
      for (int off = 1; off < 64; off <<= 1) {
        unsigned long long v2 = __shfl_xor(mk, off);
        mk = v2 < mk ? v2 : mk;
      }
      int widx = (int)(mk & 1023u);
      if (lane == 0) o[kk] = widx;
      if ((widx & 63) == lane) {
        dkS[row][widx] = 0xFFFFFFFFu;
        bv = 0xFFFFFFFFu; bi = lane;
        #pragma unroll
        for (int it = 0; it < 16; it++) {
          unsigned int k = dkS[row][lane + 64 * it];
          if (k < bv) { bv = k; bi = lane + 64 * it; }
        }
      }
    }
  }
}

// ---------------------------------------------------------------------------
// K3: FUSED gather + max-rel + grouped conv, both halves per block (R15/17).
// ---------------------------------------------------------------------------
__global__ __launch_bounds__(256) void fconv_kernel(
    const float* __restrict__ x, const int* __restrict__ nn9,
    const float* __restrict__ w, const float* __restrict__ bias,
    float* __restrict__ outpre, float* __restrict__ psum,
    float* __restrict__ pss) {
  int nt = blockIdx.x;
  int g  = blockIdx.y;
  int b  = blockIdx.z;
  int n0 = nt * 112;
  int t = threadIdx.x;

  __shared__ float Wl[48][97];
  __shared__ float Hl[96][112];
  __shared__ unsigned short Il[112][K_];

  const int* isrc = nn9 + ((size_t)b * N_ + n0) * K_;
  for (int i = t; i < 112 * K_; i += 256)
    Il[i / K_][i % K_] = (unsigned short)isrc[i];
  const float* wsrc0 = w + (size_t)(g * 96) * 96;
  for (int i = t; i < 48 * 96; i += 256) Wl[i / 96][i % 96] = wsrc0[i];
  __syncthreads();

  const float* xb = x + (size_t)b * C_ * N_;
  for (int pos = t; pos < 48 * 112; pos += 256) {
    int cl = pos / 112, nl = pos % 112;
    const float* row = xb + (size_t)(g * 48 + cl) * N_;
    float xv = row[n0 + nl];
    float mx = -1e30f;
    #pragma unroll
    for (int k = 0; k < K_; k++) mx = fmaxf(mx, row[Il[nl][k]]);
    Hl[2 * cl][nl]     = xv;
    Hl[2 * cl + 1][nl] = mx - xv;
  }
  __syncthreads();

  int tx = t & 15, ty = t >> 4;
  int tidx = b * 7 + nt;

  for (int half = 0; half < 2; half++) {
    float o[3][7];
    #pragma unroll
    for (int i = 0; i < 3; i++)
      #pragma unroll
      for (int j = 0; j < 7; j++) o[i][j] = 0.f;

    for (int k = 0; k < 96; k++) {
      float w0 = Wl[ty * 3 + 0][k];
      float w1 = Wl[ty * 3 + 1][k];
      float w2 = Wl[ty * 3 + 2][k];
      #pragma unroll
      for (int j = 0; j < 7; j++) {
        float hv = Hl[k][tx * 7 + j];
        o[0][j] = __fmaf_rn(w0, hv, o[0][j]);
        o[1][j] = __fmaf_rn(w1, hv, o[1][j]);
        o[2][j] = __fmaf_rn(w2, hv, o[2][j]);
      }
    }

    #pragma unroll
    for (int i = 0; i < 3; i++) {
      int co = g * 96 + half * 48 + ty * 3 + i;
      float bv = bias[co];
      float s = 0.f, s2 = 0.f;
      float* orow = outpre + ((size_t)b * COUT_ + co) * N_ + n0 + tx * 7;
      #pragma unroll
      for (int j = 0; j < 7; j++) {
        float v = o[i][j] + bv;
        orow[j] = v;
        s += v; s2 += v * v;
      }
      #pragma unroll
      for (int off = 1; off < 16; off <<= 1) {
        s  += __shfl_xor(s, off);
        s2 += __shfl_xor(s2, off);
      }
      if (tx == 0) {
        psum[co * NTILES_ + tidx] = s;
        pss [co * NTILES_ + tidx] = s2;
      }
    }

    if (half == 0) {
      __syncthreads();
      const float* wsrc1 = w + (size_t)(g * 96 + 48) * 96;
      for (int i = t; i < 48 * 96; i += 256) Wl[i / 96][i % 96] = wsrc1[i];
      __syncthreads();
    }
  }
}

// ---------------------------------------------------------------------------
// K4: finalize BN stats -> per-channel affine a, b
// ---------------------------------------------------------------------------
__global__ __launch_bounds__(64) void stats_kernel(
    const float* __restrict__ psum, const float* __restrict__ pss,
    const float* __restrict__ gamma, const float* __restrict__ beta,
    float* __restrict__ af, float* __restrict__ bf) {
  int co = blockIdx.x;
  int l = threadIdx.x;
  double s = 0.0, s2 = 0.0;
  for (int i = l; i < NTILES_; i += 64) {
    s  += (double)psum[co * NTILES_ + i];
    s2 += (double)pss [co * NTILES_ + i];
  }
  #pragma unroll
  for (int o = 32; o > 0; o >>= 1) { s += __shfl_xor(s, o); s2 += __shfl_xor(s2, o); }
  if (l == 0) {
    const double cnt = (double)NPTS_;
    double mean = s / cnt;
    double var  = s2 / cnt - mean * mean;
    double rstd = 1.0 / sqrt(var + 1e-5);
    double a = (double)gamma[co] * rstd;
    af[co] = (float)a;
    bf[co] = (float)((double)beta[co] - mean * a);
  }
}

// ---------------------------------------------------------------------------
// K5: BN affine + exact GELU + fp32 store
// ---------------------------------------------------------------------------
__global__ __launch_bounds__(256) void act_kernel(
    const float* __restrict__ outpre, const float* __restrict__ af,
    const float* __restrict__ bf, float* __restrict__ out) {
  size_t i = ((size_t)blockIdx.x * 256 + threadIdx.x) * 4;
  int co = (int)((i / N_) % COUT_);
  float a = af[co], c = bf[co];
  float4 v = *(const float4*)(outpre + i);
  float y0 = a * v.x + c, y1 = a * v.y + c, y2 = a * v.z + c, y3 = a * v.w + c;
  const float is2 = 0.70710678118654752f;
  float4 r;
  r.x = 0.5f * y0 * (1.0f + erff(y0 * is2));
  r.y = 0.5f * y1 * (1.0f + erff(y1 * is2));
  r.z = 0.5f * y2 * (1.0f + erff(y2 * is2));
  r.w = 0.5f * y3 * (1.0f + erff(y3 * is2));
  *reinterpret_cast<float4*>(out + i) = r;
}

// ---------------------------------------------------------------------------
extern "C" void kernel_launch(void* const* d_in, const int* in_sizes, int n_in,
                              void* d_out, int out_size, void* d_ws, size_t ws_size,
                              hipStream_t stream) {
  const float* x      = (const float*)d_in[0];
  const float* conv_w = (const float*)d_in[1];
  const float* conv_b = (const float*)d_in[2];
  const float* gamma  = (const float*)d_in[3];
  const float* beta   = (const float*)d_in[4];
  float* out = (float*)d_out;

  // ws layout (float offsets), ~65 MB:
  float* buf0 = (float*)d_ws;
  short8* fragH = (short8*)buf0;                         // [0, 3145728)
  short8* fragL = (short8*)(buf0 + 3145728);             // [3145728, 6291456)
  float*  sqp   = buf0 + 6291456;                        // [6291456, 6324224)
  int*    nn9   = (int*)(buf0 + 6324224);                // [6324224, 6550016)
  float*  outpre = buf0 + 6550016;                       // [6550016, 16183808)
  float*  psum  = buf0 + 16183808;
  float*  pss   = psum + COUT_ * NTILES_;
  float*  af    = pss + COUT_ * NTILES_;
  float*  bfv   = af + COUT_;

  hipLaunchKernelGGL(padfrag_kernel, dim3(720), dim3(256), 0, stream,
                     fragH, fragL);
  hipLaunchKernelGGL(norm_kernel, dim3(NPTS_ / 64), dim3(256), 0, stream,
                     x, fragH, fragL, sqp);
  hipLaunchKernelGGL(knn_kernel, dim3(49 * B_), dim3(512), 0, stream,
                     fragH, fragL, sqp, nn9);
  hipLaunchKernelGGL(fconv_kernel, dim3(7, 4, B_), dim3(256), 0, stream,
                     x, nn9, conv_w, conv_b, outpre, psum, pss);
  hipLaunchKernelGGL(stats_kernel, dim3(COUT_), dim3(64), 0, stream,
                     psum, pss, gamma, beta, af, bfv);
  hipLaunchKernelGGL(act_kernel, dim3((B_ * COUT_ * N_) / (256 * 4)), dim3(256), 0, stream,
                     outpre, af, bfv, out);
}

// Round 19
// 209.589 us; speedup vs baseline: 1.6525x; 1.1602x over previous
//
#include <hip/hip_runtime.h>

#define B_    32
#define C_    192
#define N_    784
#define NP_   1024        // sqp row stride (pad never read)
#define K_    9
#define COUT_ 384
#define NPTS_ (B_ * N_)   // 25088
#define NTILES_ 224       // 32 b * 7 ntiles
#define DKW_  836         // dkS row stride (bank-friendly, >= 13*64=832)

typedef __attribute__((ext_vector_type(8))) short short8;   // 8 bf16 = 4 VGPR
typedef __attribute__((ext_vector_type(4))) float f32x4;    // MFMA acc

// ordered-uint transform: monotone map float -> uint
__device__ __forceinline__ unsigned int ford(float f) {
  unsigned int u = __float_as_uint(f);
  return u ^ ((u & 0x80000000u) ? 0xFFFFFFFFu : 0x80000000u);
}
// fp32 -> bf16 (RNE)
__device__ __forceinline__ unsigned short f2bf(float f) {
  unsigned int u = __float_as_uint(f);
  u += 0x7FFFu + ((u >> 16) & 1u);
  return (unsigned short)(u >> 16);
}
__device__ __forceinline__ float bf2f(unsigned short h) {
  return __uint_as_float(((unsigned int)h) << 16);
}

// ---------------------------------------------------------------------------
// K1: norm + FUSED frag pack (proven R17). Block = 64 pts x 4 c-groups.
// Writes only groups g = n>>4 in [0,49) — pad groups never touched or read.
// ---------------------------------------------------------------------------
__global__ __launch_bounds__(256) void norm_kernel(
    const float* __restrict__ x, short8* __restrict__ fragH,
    short8* __restrict__ fragL, float* __restrict__ sqp) {
  int t = threadIdx.x;
  int pl = t & 63, cg = t >> 6;
  int p = blockIdx.x * 64 + pl;
  int b = p / N_, n = p % N_;
  const float* xb = x + (size_t)b * C_ * N_ + n;

  __shared__ float red[4][64];
  __shared__ float nrmS[64];

  float part = 0.f;
  #pragma unroll 8
  for (int j = 0; j < 48; j++) {
    float v = xb[(size_t)(cg * 48 + j) * N_];
    part = __fmaf_rn(v, v, part);
  }
  red[cg][pl] = part;
  __syncthreads();
  if (t < 64) {
    float ssq = __fadd_rn(__fadd_rn(red[0][t], red[1][t]),
                          __fadd_rn(red[2][t], red[3][t]));
    nrmS[t] = fmaxf(__fsqrt_rn(ssq), 1e-12f);
  }
  __syncthreads();
  float nrm = nrmS[pl];
  int g = n >> 4, li = n & 15;
  float p2 = 0.f;
  #pragma unroll
  for (int s = 0; s < 6; s++) {
    int kslot = cg * 6 + s;          // 0..23
    int ks = kslot >> 2, kq = kslot & 3;
    union { short8 v; unsigned short u[8]; } ph, plo;
    #pragma unroll
    for (int j = 0; j < 8; j++) {
      float a = __fdiv_rn(xb[(size_t)(kslot * 8 + j) * N_], nrm);
      unsigned short h = f2bf(a);
      ph.u[j]  = h;
      plo.u[j] = f2bf(__fsub_rn(a, bf2f(h)));
      p2 = __fmaf_rn(a, a, p2);
    }
    size_t idx = (((size_t)b * 6 + ks) * 64 + g) * 64 + (kq * 16 + li);
    fragH[idx] = ph.v;
    fragL[idx] = plo.v;
  }
  red[cg][pl] = p2;
  __syncthreads();
  if (t < 64) {
    float sq = __fadd_rn(__fadd_rn(red[0][t], red[1][t]),
                         __fadd_rn(red[2][t], red[3][t]));
    int pp = blockIdx.x * 64 + t;
    sqp[(size_t)(pp / N_) * NP_ + (pp % N_)] = sq;
  }
}

// ---------------------------------------------------------------------------
// K2: MFMA KNN — real columns only (g in [0,49), cols < 784). 256 thr.
//  Wave ranges {0-12, 13-25, 26-38, 39-48}: pairs + odd single tail.
//  Distance chains bit-identical to R17 for real cols. cs from global
//  (L2-hot), dkS[16][836] = 53.5 KB; selection = 13-strip scan (proven).
// ---------------------------------------------------------------------------
__global__ __launch_bounds__(256) void knn_kernel(
    const short8* __restrict__ fragH, const short8* __restrict__ fragL,
    const float* __restrict__ sqp, int* __restrict__ nn9) {
  int wg = blockIdx.x;
  int r = wg & 7, j = wg >> 3;
  int b  = r + 8 * (j / 49);
  int qt = j % 49;
  int q0 = qt * 16;
  int t = threadIdx.x, lane = t & 63, w = t >> 6;

  __shared__ unsigned int dkS[16][DKW_];  // 53.5 KB keys
  __shared__ float qsqS[16];

  // preset pad cols [784, 836) to MAX (scanned strips cover up to 831)
  for (int i = t; i < 16 * 52; i += 256)
    dkS[i / 52][784 + i % 52] = 0xFFFFFFFFu;
  if (t < 16) qsqS[t] = sqp[(size_t)b * NP_ + q0 + t];
  __syncthreads();

  const float* sqb = sqp + (size_t)b * NP_;
  const short8* fH = fragH + (size_t)b * 6 * 64 * 64;
  const short8* fL = fragL + (size_t)b * 6 * 64 * 64;

  short8 aH[6], aL[6];
  #pragma unroll
  for (int ks = 0; ks < 6; ks++) {
    aH[ks] = fH[((size_t)ks * 64 + qt) * 64 + lane];
    aL[ks] = fL[((size_t)ks * 64 + qt) * 64 + lane];
  }

  int colL = lane & 15, rq = lane >> 4;
  const int wstart = (w == 0) ? 0 : (w == 1) ? 13 : (w == 2) ? 26 : 39;
  const int wend   = (w == 0) ? 13 : (w == 1) ? 26 : (w == 2) ? 39 : 49;

  int g = wstart;
  for (; g + 1 < wend; g += 2) {
    int g0 = g, g1 = g + 1;
    f32x4 a00 = {0.f, 0.f, 0.f, 0.f}, a01 = a00, a02 = a00;
    f32x4 a10 = a00, a11 = a00, a12 = a00;
    #pragma unroll
    for (int ks = 0; ks < 6; ks++) {
      short8 b0h = fH[((size_t)ks * 64 + g0) * 64 + lane];
      short8 b0l = fL[((size_t)ks * 64 + g0) * 64 + lane];
      short8 b1h = fH[((size_t)ks * 64 + g1) * 64 + lane];
      short8 b1l = fL[((size_t)ks * 64 + g1) * 64 + lane];
      a00 = __builtin_amdgcn_mfma_f32_16x16x32_bf16(aH[ks], b0h, a00, 0, 0, 0);
      a01 = __builtin_amdgcn_mfma_f32_16x16x32_bf16(aH[ks], b0l, a01, 0, 0, 0);
      a02 = __builtin_amdgcn_mfma_f32_16x16x32_bf16(aL[ks], b0h, a02, 0, 0, 0);
      a10 = __builtin_amdgcn_mfma_f32_16x16x32_bf16(aH[ks], b1h, a10, 0, 0, 0);
      a11 = __builtin_amdgcn_mfma_f32_16x16x32_bf16(aH[ks], b1l, a11, 0, 0, 0);
      a12 = __builtin_amdgcn_mfma_f32_16x16x32_bf16(aL[ks], b1h, a12, 0, 0, 0);
    }
    float cs0 = sqb[g0 * 16 + colL];
    float cs1 = sqb[g1 * 16 + colL];
    #pragma unroll
    for (int rr = 0; rr < 4; rr++) {
      int row = rq * 4 + rr;
      float qs = qsqS[row];
      float g0v = __fadd_rn(__fadd_rn(a00[rr], a01[rr]), a02[rr]);
      float g1v = __fadd_rn(__fadd_rn(a10[rr], a11[rr]), a12[rr]);
      float d0 = __fadd_rn(__fsub_rn(qs, __fmul_rn(2.0f, g0v)), cs0);
      float d1 = __fadd_rn(__fsub_rn(qs, __fmul_rn(2.0f, g1v)), cs1);
      dkS[row][g0 * 16 + colL] = ford(d0);
      dkS[row][g1 * 16 + colL] = ford(d1);
    }
  }
  if (g < wend) {                       // odd tail: single group
    int g0 = g;
    f32x4 a00 = {0.f, 0.f, 0.f, 0.f}, a01 = a00, a02 = a00;
    #pragma unroll
    for (int ks = 0; ks < 6; ks++) {
      short8 b0h = fH[((size_t)ks * 64 + g0) * 64 + lane];
      short8 b0l = fL[((size_t)ks * 64 + g0) * 64 + lane];
      a00 = __builtin_amdgcn_mfma_f32_16x16x32_bf16(aH[ks], b0h, a00, 0, 0, 0);
      a01 = __builtin_amdgcn_mfma_f32_16x16x32_bf16(aH[ks], b0l, a01, 0, 0, 0);
      a02 = __builtin_amdgcn_mfma_f32_16x16x32_bf16(aL[ks], b0h, a02, 0, 0, 0);
    }
    float cs0 = sqb[g0 * 16 + colL];
    #pragma unroll
    for (int rr = 0; rr < 4; rr++) {
      int row = rq * 4 + rr;
      float qs = qsqS[row];
      float g0v = __fadd_rn(__fadd_rn(a00[rr], a01[rr]), a02[rr]);
      float d0 = __fadd_rn(__fsub_rn(qs, __fmul_rn(2.0f, g0v)), cs0);
      dkS[row][g0 * 16 + colL] = ford(d0);
    }
  }
  __syncthreads();

  for (int s = 0; s < 4; s++) {
    int row = w * 4 + s;
    unsigned int bv = 0xFFFFFFFFu; int bi = lane;
    #pragma unroll
    for (int it = 0; it < 13; it++) {
      unsigned int k = dkS[row][lane + 64 * it];
      if (k < bv) { bv = k; bi = lane + 64 * it; }
    }
    int* o = nn9 + ((size_t)b * N_ + q0 + row) * K_;
    for (int kk = 0; kk < K_; kk++) {
      unsigned long long mk = ((unsigned long long)bv << 10) | (unsigned int)bi;
      #pragma unroll
      for (int off = 1; off < 64; off <<= 1) {
        unsigned long long v2 = __shfl_xor(mk, off);
        mk = v2 < mk ? v2 : mk;
      }
      int widx = (int)(mk & 1023u);
      if (lane == 0) o[kk] = widx;
      if ((widx & 63) == lane) {
        dkS[row][widx] = 0xFFFFFFFFu;
        bv = 0xFFFFFFFFu; bi = lane;
        #pragma unroll
        for (int it = 0; it < 13; it++) {
          unsigned int k = dkS[row][lane + 64 * it];
          if (k < bv) { bv = k; bi = lane + 64 * it; }
        }
      }
    }
  }
}

// ---------------------------------------------------------------------------
// K3: FUSED gather + max-rel + grouped conv, both halves per block (R15/17).
// ---------------------------------------------------------------------------
__global__ __launch_bounds__(256) void fconv_kernel(
    const float* __restrict__ x, const int* __restrict__ nn9,
    const float* __restrict__ w, const float* __restrict__ bias,
    float* __restrict__ outpre, float* __restrict__ psum,
    float* __restrict__ pss) {
  int nt = blockIdx.x;
  int g  = blockIdx.y;
  int b  = blockIdx.z;
  int n0 = nt * 112;
  int t = threadIdx.x;

  __shared__ float Wl[48][97];
  __shared__ float Hl[96][112];
  __shared__ unsigned short Il[112][K_];

  const int* isrc = nn9 + ((size_t)b * N_ + n0) * K_;
  for (int i = t; i < 112 * K_; i += 256)
    Il[i / K_][i % K_] = (unsigned short)isrc[i];
  const float* wsrc0 = w + (size_t)(g * 96) * 96;
  for (int i = t; i < 48 * 96; i += 256) Wl[i / 96][i % 96] = wsrc0[i];
  __syncthreads();

  const float* xb = x + (size_t)b * C_ * N_;
  for (int pos = t; pos < 48 * 112; pos += 256) {
    int cl = pos / 112, nl = pos % 112;
    const float* row = xb + (size_t)(g * 48 + cl) * N_;
    float xv = row[n0 + nl];
    float mx = -1e30f;
    #pragma unroll
    for (int k = 0; k < K_; k++) mx = fmaxf(mx, row[Il[nl][k]]);
    Hl[2 * cl][nl]     = xv;
    Hl[2 * cl + 1][nl] = mx - xv;
  }
  __syncthreads();

  int tx = t & 15, ty = t >> 4;
  int tidx = b * 7 + nt;

  for (int half = 0; half < 2; half++) {
    float o[3][7];
    #pragma unroll
    for (int i = 0; i < 3; i++)
      #pragma unroll
      for (int j = 0; j < 7; j++) o[i][j] = 0.f;

    for (int k = 0; k < 96; k++) {
      float w0 = Wl[ty * 3 + 0][k];
      float w1 = Wl[ty * 3 + 1][k];
      float w2 = Wl[ty * 3 + 2][k];
      #pragma unroll
      for (int j = 0; j < 7; j++) {
        float hv = Hl[k][tx * 7 + j];
        o[0][j] = __fmaf_rn(w0, hv, o[0][j]);
        o[1][j] = __fmaf_rn(w1, hv, o[1][j]);
        o[2][j] = __fmaf_rn(w2, hv, o[2][j]);
      }
    }

    #pragma unroll
    for (int i = 0; i < 3; i++) {
      int co = g * 96 + half * 48 + ty * 3 + i;
      float bv = bias[co];
      float s = 0.f, s2 = 0.f;
      float* orow = outpre + ((size_t)b * COUT_ + co) * N_ + n0 + tx * 7;
      #pragma unroll
      for (int j = 0; j < 7; j++) {
        float v = o[i][j] + bv;
        orow[j] = v;
        s += v; s2 += v * v;
      }
      #pragma unroll
      for (int off = 1; off < 16; off <<= 1) {
        s  += __shfl_xor(s, off);
        s2 += __shfl_xor(s2, off);
      }
      if (tx == 0) {
        psum[co * NTILES_ + tidx] = s;
        pss [co * NTILES_ + tidx] = s2;
      }
    }

    if (half == 0) {
      __syncthreads();
      const float* wsrc1 = w + (size_t)(g * 96 + 48) * 96;
      for (int i = t; i < 48 * 96; i += 256) Wl[i / 96][i % 96] = wsrc1[i];
      __syncthreads();
    }
  }
}

// ---------------------------------------------------------------------------
// K4: finalize BN stats -> per-channel affine a, b
// ---------------------------------------------------------------------------
__global__ __launch_bounds__(64) void stats_kernel(
    const float* __restrict__ psum, const float* __restrict__ pss,
    const float* __restrict__ gamma, const float* __restrict__ beta,
    float* __restrict__ af, float* __restrict__ bf) {
  int co = blockIdx.x;
  int l = threadIdx.x;
  double s = 0.0, s2 = 0.0;
  for (int i = l; i < NTILES_; i += 64) {
    s  += (double)psum[co * NTILES_ + i];
    s2 += (double)pss [co * NTILES_ + i];
  }
  #pragma unroll
  for (int o = 32; o > 0; o >>= 1) { s += __shfl_xor(s, o); s2 += __shfl_xor(s2, o); }
  if (l == 0) {
    const double cnt = (double)NPTS_;
    double mean = s / cnt;
    double var  = s2 / cnt - mean * mean;
    double rstd = 1.0 / sqrt(var + 1e-5);
    double a = (double)gamma[co] * rstd;
    af[co] = (float)a;
    bf[co] = (float)((double)beta[co] - mean * a);
  }
}

// ---------------------------------------------------------------------------
// K5: BN affine + exact GELU + fp32 store
// ---------------------------------------------------------------------------
__global__ __launch_bounds__(256) void act_kernel(
    const float* __restrict__ outpre, const float* __restrict__ af,
    const float* __restrict__ bf, float* __restrict__ out) {
  size_t i = ((size_t)blockIdx.x * 256 + threadIdx.x) * 4;
  int co = (int)((i / N_) % COUT_);
  float a = af[co], c = bf[co];
  float4 v = *(const float4*)(outpre + i);
  float y0 = a * v.x + c, y1 = a * v.y + c, y2 = a * v.z + c, y3 = a * v.w + c;
  const float is2 = 0.70710678118654752f;
  float4 r;
  r.x = 0.5f * y0 * (1.0f + erff(y0 * is2));
  r.y = 0.5f * y1 * (1.0f + erff(y1 * is2));
  r.z = 0.5f * y2 * (1.0f + erff(y2 * is2));
  r.w = 0.5f * y3 * (1.0f + erff(y3 * is2));
  *reinterpret_cast<float4*>(out + i) = r;
}

// ---------------------------------------------------------------------------
extern "C" void kernel_launch(void* const* d_in, const int* in_sizes, int n_in,
                              void* d_out, int out_size, void* d_ws, size_t ws_size,
                              hipStream_t stream) {
  const float* x      = (const float*)d_in[0];
  const float* conv_w = (const float*)d_in[1];
  const float* conv_b = (const float*)d_in[2];
  const float* gamma  = (const float*)d_in[3];
  const float* beta   = (const float*)d_in[4];
  float* out = (float*)d_out;

  // ws layout (float offsets), ~65 MB:
  float* buf0 = (float*)d_ws;
  short8* fragH = (short8*)buf0;                         // [0, 3145728)
  short8* fragL = (short8*)(buf0 + 3145728);             // [3145728, 6291456)
  float*  sqp   = buf0 + 6291456;                        // [6291456, 6324224)
  int*    nn9   = (int*)(buf0 + 6324224);                // [6324224, 6550016)
  float*  outpre = buf0 + 6550016;                       // [6550016, 16183808)
  float*  psum  = buf0 + 16183808;
  float*  pss   = psum + COUT_ * NTILES_;
  float*  af    = pss + COUT_ * NTILES_;
  float*  bfv   = af + COUT_;

  hipLaunchKernelGGL(norm_kernel, dim3(NPTS_ / 64), dim3(256), 0, stream,
                     x, fragH, fragL, sqp);
  hipLaunchKernelGGL(knn_kernel, dim3(49 * B_), dim3(256), 0, stream,
                     fragH, fragL, sqp, nn9);
  hipLaunchKernelGGL(fconv_kernel, dim3(7, 4, B_), dim3(256), 0, stream,
                     x, nn9, conv_w, conv_b, outpre, psum, pss);
  hipLaunchKernelGGL(stats_kernel, dim3(COUT_), dim3(64), 0, stream,
                     psum, pss, gamma, beta, af, bfv);
  hipLaunchKernelGGL(act_kernel, dim3((B_ * COUT_ * N_) / (256 * 4)), dim3(256), 0, stream,
                     outpre, af, bfv, out);
}